// Round 12
// baseline (112.276 us; speedup 1.0000x reference)
//
#include <hip/hip_runtime.h>
#include <hip/hip_bf16.h>

#define F 64
#define R 64
#define O 64

typedef short bf16x8 __attribute__((ext_vector_type(8)));
typedef float f32x4 __attribute__((ext_vector_type(4)));
typedef float f32x2 __attribute__((ext_vector_type(2)));

static __device__ __forceinline__ unsigned short f2bf(float f) {
    unsigned u = __builtin_bit_cast(unsigned, f);
    unsigned r = (u + 0x7fffu + ((u >> 16) & 1u)) >> 16;
    return (unsigned short)r;
}

// ---------------------------------------------------------------------------
// Prep kernel (flat, 146 blocks x 256) — proven variant.
//   threads [0, 33280): pack W (fp32) -> Wpk (bf16, MFMA B-fragment order):
//     dst bf16x8 idx = ((nt*65 + f)*2 + kk)*64 + lane
//     elem j = W[o][f*64 + r], o = nt*16+(lane&15), r = (lane>>4)*8 + j + kk*32
//   threads [33280, 37376): prm[u] = {s, mn*s, t, c}, u = f*64 + r
// ---------------------------------------------------------------------------
__global__ __launch_bounds__(256) void fq_prep(
        const float* __restrict__ tt, const float* __restrict__ mean,
        const float* __restrict__ std_, const float* __restrict__ W,
        float* __restrict__ prm, unsigned short* __restrict__ Wpk)
{
    const int tg = blockIdx.x * 256 + threadIdx.x;
    if (tg < 65 * 512) {
        const int f    = tg >> 9;
        const int u8   = tg & 511;
        const int lane = u8 & 63;
        const int kk   = (u8 >> 6) & 1;
        const int nt   = u8 >> 7;
        const int o    = nt * 16 + (lane & 15);
        const int rb   = ((lane >> 4) << 3) + kk * 32;
        const float* src = W + o * 4160 + f * 64 + rb;
        unsigned short v[8];
#pragma unroll
        for (int j = 0; j < 8; ++j) v[j] = f2bf(src[j]);
        const int dst = ((nt * 65 + f) * 2 + kk) * 64 + lane;
        *(bf16x8*)(Wpk + (size_t)dst * 8) = *(bf16x8*)v;
    } else if (tg < 65 * 512 + 4096) {
        const int u = tg - 65 * 512;
        float sd = std_[u];
        float mn = mean[u];
        float th = tanhf(tt[u]);
        float s  = 1.2011224087864498f / sd;  // sqrt(log2(e)) / std
        float4 p;
        p.x = s;
        p.y = mn * s;
        p.z = th;
        p.w = 0.5f * (1.0f - th);
        ((float4*)prm)[u] = p;
    }
}

// ---------------------------------------------------------------------------
// k1: firing strengths only. No LDS, no barriers. 4 rows per wave (lane = r),
// 2048 blocks x 256 thr = 8192 waves = 32/CU occupancy cap. Trans-bound by
// design: the whole chip saturates the exp2 pipe (~7 us floor).
// Writes raw fire (bf16) to fireb[b][r] and 1/rowsum (fp32) to rinvg[b].
// ---------------------------------------------------------------------------
__global__ __launch_bounds__(256, 8) void fq_fire(
        const float* __restrict__ X,
        const float4* __restrict__ prm,
        unsigned short* __restrict__ fireb,
        float* __restrict__ rinvg)
{
    const int t    = threadIdx.x;
    const int lane = t & 63;
    const int w    = __builtin_amdgcn_readfirstlane(t >> 6);
    const int row0 = (blockIdx.x * 4 + w) * 4;   // 4 rows per wave

    f32x2 fire2[2] = {(f32x2){1.f, 1.f}, (f32x2){1.f, 1.f}};
    const float* Xw = X + (size_t)row0 * 64;
    float4 p = prm[lane];
#pragma unroll 4
    for (int f = 0; f < F; ++f) {
        const int pf = (f + 1 < 64) ? f + 1 : 63;
        float4 pn = prm[pf * 64 + lane];       // distance-1 prefetch
        f32x2 px = (f32x2){p.x, p.x};
        f32x2 py = (f32x2){-p.y, -p.y};
        f32x2 pt = (f32x2){p.z, p.z};
        f32x2 pc = (f32x2){p.w, p.w};
#pragma unroll
        for (int i = 0; i < 2; ++i) {
            f32x2 x;
            x.x = Xw[(2 * i) * 64 + f];        // wave-uniform -> s_load
            x.y = Xw[(2 * i + 1) * 64 + f];
            f32x2 z  = __builtin_elementwise_fma(x, px, py);
            f32x2 nz = -(z * z);
            f32x2 g;
            g.x = __builtin_amdgcn_exp2f(nz.x);
            g.y = __builtin_amdgcn_exp2f(nz.y);
            f32x2 m = __builtin_elementwise_fma(g, pt, pc);
            fire2[i] = fire2[i] * m;
        }
        p = pn;
    }

    // coalesced bf16 stores (64 lanes x 2 B = 128 B per row)
#pragma unroll
    for (int i = 0; i < 2; ++i) {
        fireb[(size_t)(row0 + 2 * i) * 64 + lane]     = f2bf(fire2[i].x);
        fireb[(size_t)(row0 + 2 * i + 1) * 64 + lane] = f2bf(fire2[i].y);
    }
    // butterfly row sums (fp32, unrounded) -> rinv
#pragma unroll
    for (int i = 0; i < 2; ++i) {
        float sx = fire2[i].x, sy = fire2[i].y;
#pragma unroll
        for (int d = 1; d < 64; d <<= 1) {
            sx += __shfl_xor(sx, d);
            sy += __shfl_xor(sy, d);
        }
        if (lane == 0) {
            rinvg[row0 + 2 * i]     = 1.0f / sx;
            rinvg[row0 + 2 * i + 1] = 1.0f / sy;
        }
    }
}

// ---------------------------------------------------------------------------
// k2: GEMM only. block = 128 rows, 1024 thr, 16 waves = 4 nt x 4 g.
// The 4 g-waves of each nt run IDENTICAL code on IDENTICAL W addresses from
// the first instruction (no divergent prior phase) -> L1 serves 3 of 4,
// cutting L2 W-traffic ~4x. 256 blocks = 1 per CU. All waves enter the
// K-loop immediately; MFMA floor ~7 us. Normalization in epilogue.
// ---------------------------------------------------------------------------
__global__ __launch_bounds__(1024, 4) void fq_gemm(
        const float* __restrict__ X,
        const unsigned short* __restrict__ fireb,
        const float* __restrict__ rinvg,
        const bf16x8* __restrict__ Wp,
        float* __restrict__ out)
{
    __shared__ __align__(16) float xt[64][132];   // [f][row], 128 rows + pad

    const int t    = threadIdx.x;
    const int lane = t & 63;
    const int w    = __builtin_amdgcn_readfirstlane(t >> 6);  // 0..15
    const int nt   = w >> 2;
    const int g    = w & 3;
    const int b0   = blockIdx.x * 128;

    const int m_in = lane & 15;
    const int quad = lane >> 4;
    const int q8   = quad * 8;
    const f32x4 z4 = (f32x4){0.f, 0.f, 0.f, 0.f};

    // ---- early independent loads: W prefetch, wfrag, rinv ------------------
    const bf16x8* wpb = Wp + (size_t)(nt * 130) * 64 + lane;
    bf16x8 pe0 = wpb[0 * 64],  pe1 = wpb[1 * 64];
    bf16x8 po0 = wpb[2 * 64],  po1 = wpb[3 * 64];

    bf16x8 wfrag[2][2];
    f32x4 rv[2];
#pragma unroll
    for (int mm = 0; mm < 2; ++mm) {
        const int myrow = b0 + 32 * g + 16 * mm + m_in;
        wfrag[mm][0] = *(const bf16x8*)(fireb + (size_t)myrow * 64 + q8);
        wfrag[mm][1] = *(const bf16x8*)(fireb + (size_t)myrow * 64 + q8 + 32);
        rv[mm] = *(const f32x4*)(rinvg + b0 + 32 * g + 16 * mm + quad * 4);
    }

    // ---- xt fill: coalesced float4 reads, transposed LDS write -------------
    {
        const int xrow = t >> 3;            // 0..127
        const int xf8  = (t & 7) * 8;
        float4 x0 = *(const float4*)(X + (size_t)(b0 + xrow) * 64 + xf8);
        float4 x1 = *(const float4*)(X + (size_t)(b0 + xrow) * 64 + xf8 + 4);
#pragma unroll
        for (int j = 0; j < 4; ++j) {
            xt[xf8 + j][xrow]     = x0[j];
            xt[xf8 + 4 + j][xrow] = x1[j];
        }
    }
    __syncthreads();

    // ---- K-loop: dist-2 even/odd W prefetch (proven r9 loop) ---------------
    f32x4 acc[2];
    acc[0] = z4; acc[1] = z4;

#pragma unroll 2
    for (int i = 0; i < 32; ++i) {
        const int fe = 2 * i, fo = 2 * i + 1;
        bf16x8 ce0 = pe0, ce1 = pe1, co0 = po0, co1 = po1;
        const int se = (fe + 2 <= 64) ? fe + 2 : 64;   // clamp to bias slab
        const int so = (fo + 2 <= 64) ? fo + 2 : 64;
        pe0 = wpb[(2 * se) * 64];  pe1 = wpb[(2 * se + 1) * 64];
        po0 = wpb[(2 * so) * 64];  po1 = wpb[(2 * so + 1) * 64];
#pragma unroll
        for (int mm = 0; mm < 2; ++mm) {
            f32x4 U = __builtin_amdgcn_mfma_f32_16x16x32_bf16(wfrag[mm][0], ce0, z4, 0, 0, 0);
            U = __builtin_amdgcn_mfma_f32_16x16x32_bf16(wfrag[mm][1], ce1, U, 0, 0, 0);
            f32x4 xv = *(const f32x4*)&xt[fe][32 * g + 16 * mm + quad * 4];
#pragma unroll
            for (int reg = 0; reg < 4; ++reg)
                acc[mm][reg] = __builtin_fmaf(xv[reg], U[reg], acc[mm][reg]);
        }
#pragma unroll
        for (int mm = 0; mm < 2; ++mm) {
            f32x4 U = __builtin_amdgcn_mfma_f32_16x16x32_bf16(wfrag[mm][0], co0, z4, 0, 0, 0);
            U = __builtin_amdgcn_mfma_f32_16x16x32_bf16(wfrag[mm][1], co1, U, 0, 0, 0);
            f32x4 xv = *(const f32x4*)&xt[fo][32 * g + 16 * mm + quad * 4];
#pragma unroll
            for (int reg = 0; reg < 4; ++reg)
                acc[mm][reg] = __builtin_fmaf(xv[reg], U[reg], acc[mm][reg]);
        }
    }

    // bias slab (x = 1): pair resident in pe0/pe1 from the exit prefetch
#pragma unroll
    for (int mm = 0; mm < 2; ++mm) {
        f32x4 U = __builtin_amdgcn_mfma_f32_16x16x32_bf16(wfrag[mm][0], pe0, z4, 0, 0, 0);
        U = __builtin_amdgcn_mfma_f32_16x16x32_bf16(wfrag[mm][1], pe1, U, 0, 0, 0);
#pragma unroll
        for (int reg = 0; reg < 4; ++reg)
            acc[mm][reg] += U[reg];
    }

    // epilogue: out = acc * rinv;  C/D: col = lane&15, row = quad*4 + reg
#pragma unroll
    for (int mm = 0; mm < 2; ++mm)
#pragma unroll
        for (int reg = 0; reg < 4; ++reg) {
            const int row = b0 + 32 * g + 16 * mm + quad * 4 + reg;
            out[(size_t)row * 64 + nt * 16 + m_in] = acc[mm][reg] * rv[mm][reg];
        }
}

extern "C" void kernel_launch(void* const* d_in, const int* in_sizes, int n_in,
                              void* d_out, int out_size, void* d_ws, size_t ws_size,
                              hipStream_t stream) {
    const float* X    = (const float*)d_in[0];
    const float* tt   = (const float*)d_in[1];
    const float* mean = (const float*)d_in[2];
    const float* std_ = (const float*)d_in[3];
    const float* W    = (const float*)d_in[4];
    float* out = (float*)d_out;

    // workspace layout:
    //   prm    fp32x4  @ 0         (64 KiB)
    //   Wpk    bf16    @ 65536     (520 KiB)
    //   fireb  bf16    @ 655360    (4 MiB)   [32768][64]
    //   rinvg  fp32    @ 4849664   (128 KiB) [32768]
    float* prm           = (float*)d_ws;
    unsigned short* Wpk  = (unsigned short*)((char*)d_ws + 65536);
    unsigned short* fb   = (unsigned short*)((char*)d_ws + 655360);
    float* rinvg         = (float*)((char*)d_ws + 4849664);

    fq_prep<<<146, 256, 0, stream>>>(tt, mean, std_, W, prm, Wpk);
    fq_fire<<<2048, 256, 0, stream>>>(X, (const float4*)prm, fb, rinvg);
    fq_gemm<<<256, 1024, 0, stream>>>(X, fb, rinvg, (const bf16x8*)Wpk, out);
}